// Round 1
// baseline (465.574 us; speedup 1.0000x reference)
//
#include <hip/hip_runtime.h>
#include <stdint.h>

#define CH 256
#define HWD 56
#define POS (HWD*HWD)        // 3136
#define BATCH 32
#define NG 4                 // 4 x uint64 = 256 channel bits
#define NTAP 9

typedef unsigned long long u64;
typedef __attribute__((ext_vector_type(8))) short short8;

// ---------------- pack weights: bit j of group g = (W[o, g*64+j, kh, kw] >= 0) ----------------
__global__ void pack_w_kernel(const float* __restrict__ W, u64* __restrict__ wbits){
    int idx = blockIdx.x*blockDim.x + threadIdx.x; // o*36 + g*9 + tap
    if (idx >= CH*NG*NTAP) return;
    int o = idx / (NG*NTAP);
    int r = idx % (NG*NTAP);
    int g = r / NTAP;
    int tap = r % NTAP;
    int kh = tap/3, kw = tap%3;
    u64 bits = 0;
    for (int j=0;j<64;j++){
        int c = g*64 + j;
        float v = W[((o*CH + c)*3 + kh)*3 + kw];
        if (v >= 0.f) bits |= (1ull<<j);
    }
    wbits[idx] = bits;
}

// ---------------- pack input signs: xbits[(b*POS+pos)*NG + g] ----------------
__global__ void pack_x_kernel(const float* __restrict__ x, u64* __restrict__ xbits){
    int idx = blockIdx.x*blockDim.x + threadIdx.x; // (b*NG + g)*POS + pos
    if (idx >= BATCH*NG*POS) return;
    int pos = idx % POS;
    int bg  = idx / POS;
    int g = bg & (NG-1);
    int b = bg >> 2;
    const float* xp = x + ((size_t)(b*CH + g*64))*POS + pos;
    u64 bits = 0;
    #pragma unroll
    for (int j=0;j<64;j++){
        float v = xp[(size_t)j*POS];
        if (v >= 0.f) bits |= (1ull<<j);
    }
    xbits[((size_t)(b*POS + pos))*NG + g] = bits;
}

// ---------------- conv via xor-popcount + per-channel integer stats ----------------
__global__ void conv_kernel(const u64* __restrict__ xbits, const u64* __restrict__ wbits,
                            short* __restrict__ y16, int* __restrict__ sumI, u64* __restrict__ sumQ){
    __shared__ u64 wl[NG*NTAP];
    int o = blockIdx.x & 255;
    int b = blockIdx.x >> 8;
    int tid = threadIdx.x;
    if (tid < NG*NTAP) wl[tid] = wbits[o*NG*NTAP + tid];
    __syncthreads();

    int lsum = 0;
    int lsq  = 0;   // <= 13 * 2304^2 = 6.9e7, fits int32
    const u64* xb = xbits + (size_t)b*POS*NG;
    short* yo = y16 + ((size_t)(b*CH + o))*POS;

    for (int p = tid; p < POS; p += 256){
        int h = p / HWD;
        int w = p - h*HWD;
        int acc = 0, V = 0;
        #pragma unroll
        for (int dh=-1; dh<=1; ++dh){
            unsigned hh = (unsigned)(h+dh);
            if (hh >= HWD) continue;
            #pragma unroll
            for (int dw=-1; dw<=1; ++dw){
                unsigned ww = (unsigned)(w+dw);
                if (ww >= HWD) continue;
                V++;
                int tap = (dh+1)*3 + (dw+1);
                const u64* xp = xb + ((size_t)(hh*HWD + ww))*NG;
                acc += __builtin_popcountll(xp[0] ^ wl[0*NTAP+tap]);
                acc += __builtin_popcountll(xp[1] ^ wl[1*NTAP+tap]);
                acc += __builtin_popcountll(xp[2] ^ wl[2*NTAP+tap]);
                acc += __builtin_popcountll(xp[3] ^ wl[3*NTAP+tap]);
            }
        }
        int y = (V<<8) - 2*acc;
        yo[p] = (short)y;
        lsum += y;
        lsq  += y*y;
    }

    // wave reduce (64 lanes) then block combine
    long long lq = (long long)lsq;
    int ls = lsum;
    for (int off=32; off; off>>=1){
        ls += __shfl_down(ls, off);
        lq += __shfl_down(lq, off);
    }
    __shared__ int       wsum[4];
    __shared__ long long wsq[4];
    int wave = tid >> 6;
    int lane = tid & 63;
    if (lane == 0){ wsum[wave]=ls; wsq[wave]=lq; }
    __syncthreads();
    if (tid == 0){
        int bs = wsum[0]+wsum[1]+wsum[2]+wsum[3];
        long long bq = wsq[0]+wsq[1]+wsq[2]+wsq[3];
        atomicAdd(&sumI[o], bs);
        atomicAdd(&sumQ[o], (u64)bq);
    }
}

// ---------------- BN coefficients from exact integer sums ----------------
__global__ void bn_prep_kernel(const int* __restrict__ sumI, const u64* __restrict__ sumQ,
                               const float* __restrict__ gamma, const float* __restrict__ beta,
                               float* __restrict__ invA, float* __restrict__ shiftA){
    int o = threadIdx.x;
    const double N = (double)(BATCH*POS);
    double mean = (double)sumI[o] / N;
    double msq  = (double)sumQ[o] / N;
    double var  = msq - mean*mean;
    double inv  = (double)gamma[o] / sqrt(var + 1e-5);
    invA[o]   = (float)inv;
    shiftA[o] = (float)((double)beta[o] - mean*inv);
}

// ---------------- apply: out = y*inv + shift + x ----------------
__global__ void apply_kernel(const short* __restrict__ y16, const float* __restrict__ x,
                             const float* __restrict__ invA, const float* __restrict__ shiftA,
                             float* __restrict__ out){
    int t = blockIdx.x*blockDim.x + threadIdx.x;
    const int total8 = BATCH*CH*POS/8;
    if (t >= total8) return;
    size_t i = (size_t)t*8;
    int c = (t / (POS/8)) & 255;        // 8 elems never cross a channel (3136 % 8 == 0)
    short8 yv = *(const short8*)(y16 + i);
    float4 x0 = *(const float4*)(x + i);
    float4 x1 = *(const float4*)(x + i + 4);
    float iv = invA[c], sh = shiftA[c];
    float4 o0, o1;
    o0.x = fmaf((float)yv[0], iv, sh) + x0.x;
    o0.y = fmaf((float)yv[1], iv, sh) + x0.y;
    o0.z = fmaf((float)yv[2], iv, sh) + x0.z;
    o0.w = fmaf((float)yv[3], iv, sh) + x0.w;
    o1.x = fmaf((float)yv[4], iv, sh) + x1.x;
    o1.y = fmaf((float)yv[5], iv, sh) + x1.y;
    o1.z = fmaf((float)yv[6], iv, sh) + x1.z;
    o1.w = fmaf((float)yv[7], iv, sh) + x1.w;
    *(float4*)(out + i)     = o0;
    *(float4*)(out + i + 4) = o1;
}

extern "C" void kernel_launch(void* const* d_in, const int* in_sizes, int n_in,
                              void* d_out, int out_size, void* d_ws, size_t ws_size,
                              hipStream_t stream) {
    const float* x     = (const float*)d_in[0];
    const float* W     = (const float*)d_in[1];
    const float* gamma = (const float*)d_in[2];
    const float* beta  = (const float*)d_in[3];
    float* out = (float*)d_out;

    char* ws = (char*)d_ws;
    // layout (bytes):
    //   y16    @ 0          : 32*256*3136*2 = 51,380,224
    //   xbits  @ 51,380,224 : 32*3136*4*8   =  3,211,264
    //   wbits  @ 54,591,488 : 256*36*8      =     73,728
    //   sumI   @ 54,665,216 : 256*4
    //   sumQ   @ 54,666,240 : 256*8
    //   invA   @ 54,668,288 : 256*4
    //   shiftA @ 54,669,312 : 256*4
    short* y16   = (short*)ws;
    u64*   xbits = (u64*)(ws + 51380224);
    u64*   wbits = (u64*)(ws + 54591488);
    int*   sumI  = (int*)(ws + 54665216);
    u64*   sumQ  = (u64*)(ws + 54666240);
    float* invA  = (float*)(ws + 54668288);
    float* shiftA= (float*)(ws + 54669312);

    // zero the stat accumulators (ws is poisoned 0xAA before every launch)
    hipMemsetAsync(sumI, 0, 3072, stream);

    // pack weights: 256*36 = 9216 words
    pack_w_kernel<<<36, 256, 0, stream>>>(W, wbits);
    // pack input signs: 32*4*3136 = 401,408 words
    pack_x_kernel<<<1568, 256, 0, stream>>>(x, xbits);
    // conv + stats: one block per (b, o)
    conv_kernel<<<BATCH*CH, 256, 0, stream>>>(xbits, wbits, y16, sumI, sumQ);
    // BN coefficients
    bn_prep_kernel<<<1, 256, 0, stream>>>(sumI, sumQ, gamma, beta, invA, shiftA);
    // normalize + residual
    apply_kernel<<<(BATCH*CH*POS/8 + 255)/256, 256, 0, stream>>>(y16, x, invA, shiftA, out);
}

// Round 2
// 383.547 us; speedup vs baseline: 1.2139x; 1.2139x over previous
//
#include <hip/hip_runtime.h>
#include <stdint.h>

#define CH 256
#define HWD 56
#define POS (HWD*HWD)        // 3136
#define BATCH 32
#define NG 4                 // 4 x uint64 = 256 channel bits
#define PADW 58
#define PADP (PADW*PADW)     // 3364 padded positions per batch

typedef unsigned long long u64;
typedef __attribute__((ext_vector_type(8))) short short8;

// ---- pack weights [o][tap][g] + per-(o,tap) padding-correction constant ----
__global__ void pack_w_kernel(const float* __restrict__ W, u64* __restrict__ wbits,
                              int* __restrict__ ctap){
    int idx = blockIdx.x*256 + threadIdx.x;   // o*9 + tap
    if (idx >= CH*9) return;
    int o = idx / 9, tap = idx % 9;
    int kh = tap/3, kw = tap%3;
    int totpop = 0;
    for (int g=0; g<4; g++){
        u64 bits = 0;
        for (int j=0; j<64; j++){
            float v = W[((o*CH + g*64 + j)*3 + kh)*3 + kw];
            bits |= (u64)(v >= 0.f) << j;
        }
        wbits[o*36 + tap*4 + g] = bits;
        totpop += __builtin_popcountll(bits);
    }
    ctap[idx] = 256 - 2*totpop;   // contribution of a zero-padded (all -1) tap
}

// ---- pack input signs into zero-padded 58x58 plane: xpad[b][ph*58+pw][g] ----
__global__ void pack_x_kernel(const float* __restrict__ x, u64* __restrict__ xpad){
    int idx = blockIdx.x*256 + threadIdx.x;   // (b*NG + g)*POS + pos
    if (idx >= BATCH*NG*POS) return;
    int pos = idx % POS;
    int bg  = idx / POS;
    int g = bg & (NG-1);
    int b = bg >> 2;
    const float* xp = x + ((size_t)(b*CH + g*64))*POS + pos;
    u64 bits = 0;
    for (int j=0; j<64; j++){
        float v = xp[(size_t)j*POS];
        bits |= (u64)(v >= 0.f) << j;
    }
    int h = pos / HWD, w = pos % HWD;
    xpad[((size_t)b*PADP + (h+1)*PADW + (w+1))*4 + g] = bits;
}

// ---- conv: block = (b, chunk of 8 o). 448 threads; thread t owns positions
// t + 448k (k=0..6) = same column w0=t%56, rows h0+8k (h0=t/56). ----
__global__ __launch_bounds__(448) void conv_kernel(
        const u64* __restrict__ xpad, const u64* __restrict__ wbits,
        const int* __restrict__ ctap,
        short* __restrict__ y16, int* __restrict__ sumI, u64* __restrict__ sumQ){
    int blk = blockIdx.x;
    int b  = blk >> 5;
    int o0 = (blk & 31) * 8;
    int t  = threadIdx.x;         // 0..447
    int w0 = t % HWD;
    int h0 = t / HWD;             // 0..7

    const u64* xb = xpad + (size_t)b*PADP*4 + (size_t)((h0+1)*PADW + (w0+1))*4;

    int acc[7][8];
    #pragma unroll
    for (int k=0;k<7;k++)
        #pragma unroll
        for (int o=0;o<8;o++) acc[k][o]=0;

    #pragma unroll 1
    for (int tap=0; tap<9; ++tap){
        int dh = tap/3 - 1, dw = tap%3 - 1;
        int toff = (dh*PADW + dw)*4;
        // block-uniform weight words (expect s_load -> SGPRs)
        u64 wt0[8], wt1[8], wt2[8], wt3[8];
        #pragma unroll
        for (int o=0;o<8;o++){
            const u64* wp = wbits + (size_t)(o0+o)*36 + tap*4;
            wt0[o]=wp[0]; wt1[o]=wp[1]; wt2[o]=wp[2]; wt3[o]=wp[3];
        }
        #pragma unroll
        for (int k=0;k<7;k++){
            const u64* xp = xb + k*(8*PADW*4) + toff;
            u64 xa=xp[0], xc=xp[1], xd=xp[2], xe=xp[3];
            #pragma unroll
            for (int o=0;o<8;o++){
                acc[k][o] += __builtin_popcountll(xa^wt0[o]) + __builtin_popcountll(xc^wt1[o])
                           + __builtin_popcountll(xd^wt2[o]) + __builtin_popcountll(xe^wt3[o]);
            }
        }
    }

    // epilogue: padding correction, y store, per-o stats
    __shared__ int       wls[7][8];
    __shared__ long long wlq[7][8];
    size_t ybase = (size_t)(b*CH + o0)*POS + t;
    bool left  = (w0 == 0);
    bool right = (w0 == HWD-1);
    int wave = t >> 6, lane = t & 63;

    #pragma unroll
    for (int oo=0; oo<8; ++oo){
        const int* cp = ctap + (size_t)(o0+oo)*9;
        int c0=cp[0],c1=cp[1],c2=cp[2],c3=cp[3],c5=cp[5],c6=cp[6],c7=cp[7],c8=cp[8];
        int R0=c0+c1+c2, R2=c6+c7+c8, C0=c0+c3+c6, C2=c2+c5+c8;
        int corrcom = (left?C0:0) + (right?C2:0);
        int topterm = (h0==0) ? (R0 - (left?c0:0) - (right?c2:0)) : 0;
        int botterm = (h0==7) ? (R2 - (left?c6:0) - (right?c8:0)) : 0;
        int ls = 0; long long lq = 0;
        #pragma unroll
        for (int k=0;k<7;k++){
            int y = 2304 - 2*acc[k][oo] - corrcom;
            if (k==0) y -= topterm;
            if (k==6) y -= botterm;
            y16[ybase + (size_t)oo*POS + k*448] = (short)y;
            ls += y;
            lq += (long long)(y*y);
        }
        for (int off=32; off; off>>=1){
            ls += __shfl_down(ls, off);
            lq += __shfl_down(lq, off);
        }
        if (lane == 0){ wls[wave][oo]=ls; wlq[wave][oo]=lq; }
    }
    __syncthreads();
    if (t < 8){
        int bs = 0; long long bq = 0;
        for (int wv=0; wv<7; ++wv){ bs += wls[wv][t]; bq += wlq[wv][t]; }
        atomicAdd(&sumI[o0+t], bs);
        atomicAdd(&sumQ[o0+t], (u64)bq);
    }
}

// ---- BN coefficients from exact integer sums ----
__global__ void bn_prep_kernel(const int* __restrict__ sumI, const u64* __restrict__ sumQ,
                               const float* __restrict__ gamma, const float* __restrict__ beta,
                               float* __restrict__ invA, float* __restrict__ shiftA){
    int o = threadIdx.x;
    const double N = (double)(BATCH*POS);
    double mean = (double)sumI[o] / N;
    double msq  = (double)sumQ[o] / N;
    double var  = msq - mean*mean;
    double inv  = (double)gamma[o] / sqrt(var + 1e-5);
    invA[o]   = (float)inv;
    shiftA[o] = (float)((double)beta[o] - mean*inv);
}

// ---- apply: out = y*inv + shift + x ----
__global__ void apply_kernel(const short* __restrict__ y16, const float* __restrict__ x,
                             const float* __restrict__ invA, const float* __restrict__ shiftA,
                             float* __restrict__ out){
    int t = blockIdx.x*blockDim.x + threadIdx.x;
    const int total8 = BATCH*CH*POS/8;
    if (t >= total8) return;
    size_t i = (size_t)t*8;
    int c = (t / (POS/8)) & 255;
    short8 yv = *(const short8*)(y16 + i);
    float4 x0 = *(const float4*)(x + i);
    float4 x1 = *(const float4*)(x + i + 4);
    float iv = invA[c], sh = shiftA[c];
    float4 o0, o1;
    o0.x = fmaf((float)yv[0], iv, sh) + x0.x;
    o0.y = fmaf((float)yv[1], iv, sh) + x0.y;
    o0.z = fmaf((float)yv[2], iv, sh) + x0.z;
    o0.w = fmaf((float)yv[3], iv, sh) + x0.w;
    o1.x = fmaf((float)yv[4], iv, sh) + x1.x;
    o1.y = fmaf((float)yv[5], iv, sh) + x1.y;
    o1.z = fmaf((float)yv[6], iv, sh) + x1.z;
    o1.w = fmaf((float)yv[7], iv, sh) + x1.w;
    *(float4*)(out + i)     = o0;
    *(float4*)(out + i + 4) = o1;
}

extern "C" void kernel_launch(void* const* d_in, const int* in_sizes, int n_in,
                              void* d_out, int out_size, void* d_ws, size_t ws_size,
                              hipStream_t stream) {
    const float* x     = (const float*)d_in[0];
    const float* W     = (const float*)d_in[1];
    const float* gamma = (const float*)d_in[2];
    const float* beta  = (const float*)d_in[3];
    float* out = (float*)d_out;

    char* ws = (char*)d_ws;
    // layout (bytes):
    //   y16   @ 0          : 32*256*3136*2      = 51,380,224
    //   xpad  @ 51,380,224 : 32*3364*4*8        =  3,444,736  (ends 54,824,960)
    //   wbits @ 54,824,960 : 256*9*4*8          =     73,728  (ends 54,898,688)
    //   ctap  @ 54,898,688 : 256*9*4            =      9,216  (ends 54,907,904)
    //   sumI  @ 54,907,904 : 1024
    //   sumQ  @ 54,908,928 : 2048
    //   invA  @ 54,910,976 : 1024
    //   shiftA@ 54,912,000 : 1024
    short* y16   = (short*)ws;
    u64*   xpad  = (u64*)(ws + 51380224);
    u64*   wbits = (u64*)(ws + 54824960);
    int*   ctap  = (int*)(ws + 54898688);
    int*   sumI  = (int*)(ws + 54907904);
    u64*   sumQ  = (u64*)(ws + 54908928);
    float* invA  = (float*)(ws + 54910976);
    float* shiftA= (float*)(ws + 54912000);

    // zero the padded bit-plane borders + stat accumulators
    hipMemsetAsync(xpad, 0, 3444736, stream);
    hipMemsetAsync(sumI, 0, 3072, stream);

    pack_w_kernel<<<9, 256, 0, stream>>>(W, wbits, ctap);
    pack_x_kernel<<<1568, 256, 0, stream>>>(x, xpad);
    conv_kernel<<<BATCH*32, 448, 0, stream>>>(xpad, wbits, ctap, y16, sumI, sumQ);
    bn_prep_kernel<<<1, 256, 0, stream>>>(sumI, sumQ, gamma, beta, invA, shiftA);
    apply_kernel<<<(BATCH*CH*POS/8 + 255)/256, 256, 0, stream>>>(y16, x, invA, shiftA, out);
}